// Round 4
// baseline (5217.422 us; speedup 1.0000x reference)
//
#include <hip/hip_runtime.h>
#include <cstddef>

#define BATCH 512
#define ESZ   256
#define HSZ   512
#define G4    2048      // 4*HS
#define SRCL  64
#define TRGL  48
#define ODIM  67

typedef __bf16  bf8v    __attribute__((ext_vector_type(8)));
typedef float   floatx4 __attribute__((ext_vector_type(4)));

__device__ __forceinline__ floatx4 MF(bf8v a, bf8v b, floatx4 c) {
    return __builtin_amdgcn_mfma_f32_16x16x32_bf16(a, b, c, 0, 0, 0);
}

// fast transcendentals: v_exp_f32 + v_rcp_f32
__device__ __forceinline__ float frcp(float x) { return __builtin_amdgcn_rcpf(x); }
__device__ __forceinline__ float fsig(float x) { return frcp(1.0f + __expf(-x)); }
__device__ __forceinline__ float ftanh(float x) { return 1.0f - 2.0f * frcp(1.0f + __expf(2.0f * x)); }

// ---------------- small prep kernels ----------------
__global__ void embed_bf16(const int* __restrict__ tok, const float* __restrict__ table,
                           __bf16* __restrict__ out, int n_rows) {
    int i = blockIdx.x * 256 + threadIdx.x;
    int row = i >> 5;
    if (row >= n_rows) return;
    int e = (i & 31) << 3;
    const float* src = table + (size_t)tok[row] * ESZ + e;
    float4 a = *(const float4*)src;
    float4 b = *(const float4*)(src + 4);
    bf8v v;
    v[0] = (__bf16)a.x; v[1] = (__bf16)a.y; v[2] = (__bf16)a.z; v[3] = (__bf16)a.w;
    v[4] = (__bf16)b.x; v[5] = (__bf16)b.y; v[6] = (__bf16)b.z; v[7] = (__bf16)b.w;
    *(bf8v*)(out + (size_t)row * ESZ + e) = v;
}

__global__ void zero_kernel(float* __restrict__ p, int n) {
    int i = blockIdx.x * 256 + threadIdx.x;
    if (i < n) p[i] = 0.f;
}

__global__ void bias_prep(const float* __restrict__ af, const float* __restrict__ bf,
                          const float* __restrict__ ab, const float* __restrict__ bb,
                          const float* __restrict__ ad, const float* __restrict__ bd,
                          float* __restrict__ of, float* __restrict__ ob, float* __restrict__ od) {
    int i = blockIdx.x * 256 + threadIdx.x;
    if (i < G4) { of[i] = af[i] + bf[i]; ob[i] = ab[i] + bb[i]; od[i] = ad[i] + bd[i]; }
}

__device__ __forceinline__ bf8v cvt8(const float* __restrict__ s) {
    float4 a = *(const float4*)s;
    float4 b = *(const float4*)(s + 4);
    bf8v v;
    v[0] = (__bf16)a.x; v[1] = (__bf16)a.y; v[2] = (__bf16)a.z; v[3] = (__bf16)a.w;
    v[4] = (__bf16)b.x; v[5] = (__bf16)b.y; v[6] = (__bf16)b.z; v[7] = (__bf16)b.w;
    return v;
}

// Wcat[n][0:256]=Wih[n], [256:768]=Whh[n]  (2048 x 768 bf16)
__global__ void wcat_bf16(const float* __restrict__ Wih, const float* __restrict__ Whh,
                          __bf16* __restrict__ Wc) {
    int i = blockIdx.x * 256 + threadIdx.x;
    int n = i / 96;
    int e = (i - n * 96) << 3;
    const float* src = (e < ESZ) ? (Wih + (size_t)n * ESZ + e)
                                 : (Whh + (size_t)n * HSZ + (e - ESZ));
    *(bf8v*)(Wc + (size_t)n * 768 + e) = cvt8(src);
}

// decWe[n][k] = dec_Wih[n][1024+k]  (2048 x 256 bf16)
__global__ void decw_bf16(const float* __restrict__ dec_Wih, __bf16* __restrict__ We) {
    int i = blockIdx.x * 256 + threadIdx.x;
    int n = i >> 5;
    int e = (i & 31) << 3;
    *(bf8v*)(We + (size_t)n * ESZ + e) =
        cvt8(dec_Wih + (size_t)n * (2 * HSZ + ESZ) + 2 * HSZ + e);
}

// WdC[n][0:1024]=dec_Wih[n][0:1024], [1024:1536]=dec_Whh[n]  (2048 x 1536 bf16)
__global__ void wdcat_bf16(const float* __restrict__ dec_Wih, const float* __restrict__ dec_Whh,
                           __bf16* __restrict__ Wd) {
    int i = blockIdx.x * 256 + threadIdx.x;
    int n = i / 192;
    int e = (i - n * 192) << 3;
    const float* src = (e < 1024) ? (dec_Wih + (size_t)n * 1280 + e)
                                  : (dec_Whh + (size_t)n * HSZ + (e - 1024));
    *(bf8v*)(Wd + (size_t)n * 1536 + e) = cvt8(src);
}

__global__ void conv_f2b(const float* __restrict__ src, __bf16* __restrict__ dst, int n8) {
    int i = blockIdx.x * 256 + threadIdx.x;
    if (i < n8) *(bf8v*)(dst + (size_t)i * 8) = cvt8(src + (size_t)i * 8);
}

// fc_out_W padded to 128 rows x 512 bf16
__global__ void fo_pad(const float* __restrict__ W, __bf16* __restrict__ dst) {
    int i = blockIdx.x * 256 + threadIdx.x;
    int r = i >> 6, e = (i & 63) << 3;
    bf8v v;
    if (r < ODIM) v = cvt8(W + (size_t)r * HSZ + e);
    else { for (int k = 0; k < 8; ++k) v[k] = (__bf16)0.f; }
    *(bf8v*)(dst + (size_t)r * HSZ + e) = v;
}

// hfb[r] = [es[63][r][0:512] | es[0][r][512:1024]]
__global__ void cat_hfb(const __bf16* __restrict__ es, __bf16* __restrict__ dst) {
    int i = blockIdx.x * 256 + threadIdx.x;
    int r = i >> 7, e = (i & 127) << 3;
    const __bf16* s = (e < HSZ) ? (es + ((size_t)(63 * BATCH + r)) * 1024 + e)
                                : (es + (size_t)r * 1024 + e);
    *(bf8v*)(dst + (size_t)r * 1024 + e) = *(const bf8v*)s;
}

// cfb[r] = bf16([cf[r] | cb[r]]) from cbuf fp32 [2][512][512]
__global__ void cat_cfb(const float* __restrict__ cbuf, __bf16* __restrict__ dst) {
    int i = blockIdx.x * 256 + threadIdx.x;
    int r = i >> 7, e = (i & 127) << 3;
    const float* s = (e < HSZ) ? (cbuf + (size_t)r * HSZ + e)
                               : (cbuf + (size_t)BATCH * HSZ + (size_t)r * HSZ + (e - HSZ));
    *(bf8v*)(dst + (size_t)r * 1024 + e) = cvt8(s);
}

// ctxh[r] = bf16([ctx[r] (1024) | hid_h[r] (512)])
__global__ void cat_ctxh(const float* __restrict__ ctx, const float* __restrict__ hid_h,
                         __bf16* __restrict__ dst) {
    int i = blockIdx.x * 256 + threadIdx.x;
    int r = i / 192;
    int e = (i - r * 192) << 3;
    const float* s = (e < 1024) ? (ctx + (size_t)r * 1024 + e)
                                : (hid_h + (size_t)r * HSZ + (e - 1024));
    *(bf8v*)(dst + (size_t)r * 1536 + e) = cvt8(s);
}

// D0s[(b*512+j)*4 + g] = D0[b*2048 + g*512 + j]
__global__ void d0_swz(const float* __restrict__ D0, float* __restrict__ D0s) {
    int i = blockIdx.x * 256 + threadIdx.x;   // 1048576
    int b = i >> 11, rest = i & 2047, g = rest >> 9, j = rest & 511;
    D0s[(((size_t)b * 512 + j) << 2) + g] = D0[i];
}

// ---------------- persistent encoder scan ----------------
// One dispatch, 64 steps. 256 blocks (1/CU): dir(2) x m-tile(8, 64 rows) x j-tile(16, 32 j).
// Block computes 64m x 128gc (4 gates x 32 j, gate-interleaved LDS rows).
// Whh panel LDS-resident across all steps; x-weights + A-frags from L2.
// Steps separated by 16-block group barriers (group = same dir,m-tile).
#define ENC_STRIDE 520   // 512 + 8 bf16 pad
__global__ __launch_bounds__(256, 1) void enc_scan(
    const __bf16* __restrict__ embE,
    __bf16* __restrict__ h0, __bf16* __restrict__ h1,
    float* __restrict__ cbuf, __bf16* __restrict__ es,
    const __bf16* __restrict__ WcF, const __bf16* __restrict__ WcB,
    const float* __restrict__ biasF, const float* __restrict__ biasB,
    unsigned int* __restrict__ cnt)
{
    __shared__ __bf16 Bs[128 * ENC_STRIDE];   // 133,120 B

    const int bid = blockIdx.x;
    const int dir = bid >> 7;
    const int rem = bid & 127;
    const int m0  = (rem >> 4) * 64;
    const int j0  = (rem & 15) * 32;
    const int grp = bid >> 4;                 // 16 groups of 16 blocks

    const __bf16* Wc   = dir ? WcB : WcF;
    const float*  bias = dir ? biasB : biasF;

    const int tid  = threadIdx.x;
    const int w    = tid >> 6, lane = tid & 63;
    const int quad = lane >> 4, l15 = lane & 15;
    const int mh   = (w & 1) * 32;            // wave m-offset in block
    const int ghi  = w >> 1;                  // LDS row half
    const int jl   = l15 + ghi * 16;          // lane's j within 32

    // stage Whh panel (cols 256..768 of Wc), rows interleaved (gate, j)
#pragma unroll 4
    for (int i = 0; i < 32; ++i) {
        int idx = tid + i * 256;
        int r = idx >> 6, ch = idx & 63;
        int gate = (r >> 4) & 3;
        int jr = (r & 15) + ((r >> 6) << 4);
        *(bf8v*)(&Bs[r * ENC_STRIDE + ch * 8]) =
            *(const bf8v*)(Wc + (size_t)(gate * HSZ + j0 + jr) * 768 + 256 + ch * 8);
    }

    // x-part B pointers (global, L2-hot) and bias preload
    const __bf16* BxP[4];
    float bsv[4];
#pragma unroll
    for (int g = 0; g < 4; ++g) {
        BxP[g] = Wc + (size_t)(g * HSZ + j0 + jl) * 768 + quad * 8;
        bsv[g] = bias[g * HSZ + j0 + jl];
    }

    const size_t dirb = (size_t)dir * BATCH * HSZ;
    const __bf16* BhBase = &Bs[(ghi * 64 + l15) * ENC_STRIDE + quad * 8];
    __syncthreads();

    for (int t = 0; t < SRCL; ++t) {
        const int tt = dir ? (SRCL - 1 - t) : t;
        const __bf16* hp = (t & 1) ? h1 : h0;
        __bf16*       hn = (t & 1) ? h0 : h1;

        floatx4 acc[2][4] = {};

        // x part: K=256, A+B from global
        const __bf16* Ax = embE + ((size_t)tt * BATCH + m0 + mh + l15) * ESZ + quad * 8;
#pragma unroll 4
        for (int kt = 0; kt < 8; ++kt) {
            bf8v a0 = *(const bf8v*)(Ax + kt * 32);
            bf8v a1 = *(const bf8v*)(Ax + 16 * ESZ + kt * 32);
#pragma unroll
            for (int g = 0; g < 4; ++g) {
                bf8v b = *(const bf8v*)(BxP[g] + kt * 32);
                acc[0][g] = MF(a0, b, acc[0][g]);
                acc[1][g] = MF(a1, b, acc[1][g]);
            }
        }
        // h part: K=512, A from global, B from LDS
        const __bf16* Ah = hp + dirb + (size_t)(m0 + mh + l15) * HSZ + quad * 8;
#pragma unroll 4
        for (int kt = 0; kt < 16; ++kt) {
            bf8v a0 = *(const bf8v*)(Ah + kt * 32);
            bf8v a1 = *(const bf8v*)(Ah + 16 * HSZ + kt * 32);
#pragma unroll
            for (int g = 0; g < 4; ++g) {
                bf8v b = *(const bf8v*)(BhBase + g * 16 * ENC_STRIDE + kt * 32);
                acc[0][g] = MF(a0, b, acc[0][g]);
                acc[1][g] = MF(a1, b, acc[1][g]);
            }
        }

        // fused LSTM epilogue: lane owns 8 (m, j=j0+jl) cells, all 4 gates in regs
        const int j = j0 + jl;
#pragma unroll
        for (int ms = 0; ms < 2; ++ms) {
            int mr = m0 + mh + ms * 16 + quad * 4;
#pragma unroll
            for (int r = 0; r < 4; ++r) {
                int m = mr + r;
                float gi = acc[ms][0][r] + bsv[0];
                float gf = acc[ms][1][r] + bsv[1];
                float gg = acc[ms][2][r] + bsv[2];
                float go = acc[ms][3][r] + bsv[3];
                size_t ci = dirb + (size_t)m * HSZ + j;
                float cn = fsig(gf) * cbuf[ci] + fsig(gi) * ftanh(gg);
                cbuf[ci] = cn;
                float hv = fsig(go) * ftanh(cn);
                hn[ci] = (__bf16)hv;
                es[((size_t)tt * BATCH + m) * (2 * HSZ) + dir * HSZ + j] = (__bf16)hv;
            }
        }

        // group barrier (release h writes to the 15 sibling j-blocks)
        if (t != SRCL - 1) {
            __threadfence();
            __syncthreads();
            if (tid == 0) {
                unsigned int* c = cnt + t * 16 + grp;
                atomicAdd(c, 1u);
                while (__hip_atomic_load(c, __ATOMIC_RELAXED, __HIP_MEMORY_SCOPE_AGENT) < 16u)
                    __builtin_amdgcn_s_sleep(8);
            }
            __syncthreads();
            __threadfence();
        }
    }
}

// ---------------- decoder v4: LDS-staged K=256 GEMM + fused LSTM ----------------
// Block 128m x 128gc (4 gates x 32 j). Full K panels in LDS, no k-loop.
#define DA_STR 264   // 256 + 8 bf16 pad
__global__ __launch_bounds__(256) void dec_v4(
    const __bf16* __restrict__ embD, const __bf16* __restrict__ We,
    const float* __restrict__ D0s, const float* __restrict__ hidc,
    __bf16* __restrict__ h_new)
{
    __shared__ __bf16 As[128 * DA_STR];
    __shared__ __bf16 Bs2[128 * DA_STR];

    const int m0 = blockIdx.y * 128;
    const int j0 = blockIdx.x * 32;
    const int tid = threadIdx.x;
    const int w = tid >> 6, lane = tid & 63;
    const int quad = lane >> 4, l15 = lane & 15;
    const int mh = (w & 1) * 64;
    const int ghi = w >> 1;
    const int jl = l15 + ghi * 16;

    // stage A and B (coalesced; B rows gate-interleaved)
#pragma unroll 4
    for (int i = 0; i < 16; ++i) {
        int idx = tid + i * 256;
        int r = idx >> 5, ch = idx & 31;
        *(bf8v*)(&As[r * DA_STR + ch * 8]) =
            *(const bf8v*)(embD + (size_t)(m0 + r) * ESZ + ch * 8);
        int gate = (r >> 4) & 3;
        int jr = (r & 15) + ((r >> 6) << 4);
        *(bf8v*)(&Bs2[r * DA_STR + ch * 8]) =
            *(const bf8v*)(We + (size_t)(gate * HSZ + j0 + jr) * ESZ + ch * 8);
    }
    __syncthreads();

    floatx4 acc[4][4] = {};
    const __bf16* BhB = &Bs2[(ghi * 64 + l15) * DA_STR + quad * 8];
#pragma unroll 4
    for (int kt = 0; kt < 8; ++kt) {
        bf8v a[4];
#pragma unroll
        for (int ms = 0; ms < 4; ++ms)
            a[ms] = *(const bf8v*)(&As[(mh + ms * 16 + l15) * DA_STR + quad * 8 + kt * 32]);
#pragma unroll
        for (int g = 0; g < 4; ++g) {
            bf8v b = *(const bf8v*)(BhB + g * 16 * DA_STR + kt * 32);
#pragma unroll
            for (int ms = 0; ms < 4; ++ms)
                acc[ms][g] = MF(a[ms], b, acc[ms][g]);
        }
    }

    const int j = j0 + jl;
#pragma unroll
    for (int ms = 0; ms < 4; ++ms) {
        int mr = m0 + mh + ms * 16 + quad * 4;
#pragma unroll
        for (int r = 0; r < 4; ++r) {
            int m = mr + r;
            int b = m & (BATCH - 1);
            floatx4 d0 = *(const floatx4*)(D0s + (((size_t)b * 512 + j) << 2));
            float gi = acc[ms][0][r] + d0[0];
            float gf = acc[ms][1][r] + d0[1];
            float gg = acc[ms][2][r] + d0[2];
            float go = acc[ms][3][r] + d0[3];
            float cn = fsig(gf) * hidc[(size_t)b * HSZ + j] + fsig(gi) * ftanh(gg);
            h_new[(size_t)m * HSZ + j] = (__bf16)(fsig(go) * ftanh(cn));
        }
    }
}

// ---------------- generic bf16 MFMA GEMM: C = A @ B^T + bias (fp32 out) ----------------
__global__ __launch_bounds__(256) void gmm_bf16(
    const __bf16* __restrict__ A, const __bf16* __restrict__ B, int K,
    const float* __restrict__ bias, float* __restrict__ C, int ldc, int N)
{
    const int tid = threadIdx.x;
    const int w = tid >> 6, lane = tid & 63;
    const int quad = lane >> 4, l15 = lane & 15;
    const int n0 = blockIdx.x * 64;
    const int mA = blockIdx.y * 64 + w * 16 + l15;

    const __bf16* Ar = A + (size_t)mA * K + quad * 8;
    const __bf16* Br[4];
#pragma unroll
    for (int ns = 0; ns < 4; ++ns)
        Br[ns] = B + (size_t)(n0 + ns * 16 + l15) * K + quad * 8;

    floatx4 acc[4] = {};
    const int KT = K >> 5;
#pragma unroll 4
    for (int kt = 0; kt < KT; ++kt) {
        bf8v a = *(const bf8v*)(Ar + kt * 32);
#pragma unroll
        for (int ns = 0; ns < 4; ++ns) {
            bf8v b = *(const bf8v*)(Br[ns] + kt * 32);
            acc[ns] = MF(a, b, acc[ns]);
        }
    }
    const int mb = blockIdx.y * 64 + w * 16 + quad * 4;
#pragma unroll
    for (int ns = 0; ns < 4; ++ns) {
        int n = n0 + ns * 16 + l15;
        if (n < N) {
#pragma unroll
            for (int r = 0; r < 4; ++r)
                C[(size_t)(mb + r) * ldc + n] = acc[ns][r] + bias[n];
        }
    }
}

// ---------------- attention ----------------
__global__ void eh_kernel(const float* __restrict__ hid_h, const float* __restrict__ eW,
                          const float* __restrict__ eb, float* __restrict__ eh) {
    int w = blockIdx.x * 4 + (threadIdx.x >> 6);
    int lane = threadIdx.x & 63;
    if (w >= BATCH) return;
    float s = 0.f;
    for (int k = lane; k < HSZ; k += 64) s += hid_h[(size_t)w * HSZ + k] * eW[k];
    for (int off = 32; off; off >>= 1) s += __shfl_down(s, off);
    if (lane == 0) eh[w] = s + eb[0];
}

__global__ void energy_kernel(const __bf16* __restrict__ es, const float* __restrict__ eW2,
                              const float* __restrict__ eh, float* __restrict__ energy) {
    int w = blockIdx.x * 4 + (threadIdx.x >> 6);
    int lane = threadIdx.x & 63;
    int s = w >> 9, b = w & 511;
    const __bf16* row = es + ((size_t)s * BATCH + b) * (2 * HSZ);
    float v = 0.f;
    for (int k = lane; k < 2 * HSZ; k += 64) v += (float)row[k] * eW2[k];
    for (int off = 32; off; off >>= 1) v += __shfl_down(v, off);
    if (lane == 0) energy[(size_t)s * BATCH + b] = fmaxf(v + eh[b], 0.f);
}

__global__ void softmax_kernel(const float* __restrict__ energy, float* __restrict__ attn) {
    int b = blockIdx.x * 4 + (threadIdx.x >> 6);
    int lane = threadIdx.x & 63;
    if (b >= BATCH) return;
    float v = energy[(size_t)lane * BATCH + b];
    float m = v;
    for (int off = 32; off; off >>= 1) m = fmaxf(m, __shfl_xor(m, off));
    float e = __expf(v - m);
    float sum = e;
    for (int off = 32; off; off >>= 1) sum += __shfl_xor(sum, off);
    attn[(size_t)lane * BATCH + b] = e / sum;
}

__global__ void context_kernel(const float* __restrict__ attn, const __bf16* __restrict__ es,
                               float* __restrict__ ctx) {
    int b = blockIdx.x;
    int j = threadIdx.x * 4;
    float a0 = 0.f, a1 = 0.f, a2 = 0.f, a3 = 0.f;
    for (int s = 0; s < SRCL; ++s) {
        float a = attn[(size_t)s * BATCH + b];
        const __bf16* r = es + ((size_t)s * BATCH + b) * (2 * HSZ) + j;
        a0 += a * (float)r[0]; a1 += a * (float)r[1];
        a2 += a * (float)r[2]; a3 += a * (float)r[3];
    }
    float4 o = make_float4(a0, a1, a2, a3);
    *(float4*)(ctx + (size_t)b * (2 * HSZ) + j) = o;
}

// ---------------- launch ----------------
extern "C" void kernel_launch(void* const* d_in, const int* in_sizes, int n_in,
                              void* d_out, int out_size, void* d_ws, size_t ws_size,
                              hipStream_t stream) {
    const int*   src      = (const int*)d_in[0];
    const int*   trg      = (const int*)d_in[1];
    const float* enc_emb  = (const float*)d_in[2];
    const float* Wih_f    = (const float*)d_in[3];
    const float* Whh_f    = (const float*)d_in[4];
    const float* bih_f    = (const float*)d_in[5];
    const float* bhh_f    = (const float*)d_in[6];
    const float* Wih_b    = (const float*)d_in[7];
    const float* Whh_b    = (const float*)d_in[8];
    const float* bih_b    = (const float*)d_in[9];
    const float* bhh_b    = (const float*)d_in[10];
    const float* fc_h_W   = (const float*)d_in[11];
    const float* fc_h_b   = (const float*)d_in[12];
    const float* fc_c_W   = (const float*)d_in[13];
    const float* fc_c_b   = (const float*)d_in[14];
    const float* dec_emb  = (const float*)d_in[15];
    const float* dec_Wih  = (const float*)d_in[16];
    const float* dec_Whh  = (const float*)d_in[17];
    const float* dec_bih  = (const float*)d_in[18];
    const float* dec_bhh  = (const float*)d_in[19];
    const float* energy_W = (const float*)d_in[20];
    const float* energy_b = (const float*)d_in[21];
    const float* fc_out_W = (const float*)d_in[22];
    const float* fc_out_b = (const float*)d_in[23];
    float* out = (float*)d_out;

    // workspace layout (float units, all 16B aligned)
    float* ws = (float*)d_ws;
    size_t o = 0;
    __bf16* embE = (__bf16*)(ws + o); o += 4194304;   // 64*512*256 bf16
    __bf16* embD = (__bf16*)(ws + o); o += 3080192;   // 47*512*256 bf16
    __bf16* es   = (__bf16*)(ws + o); o += 16777216;  // 64*512*1024 bf16
    float* zbase = ws + o;                            // h0,h1,cbuf contiguous
    __bf16* h0   = (__bf16*)(ws + o); o += 262144;    // 2*512*512 bf16
    __bf16* h1   = (__bf16*)(ws + o); o += 262144;
    float*  cbuf = ws + o;            o += 524288;    // 2*512*512 f32
    __bf16* WcF  = (__bf16*)(ws + o); o += 786432;    // 2048*768 bf16
    __bf16* WcB  = (__bf16*)(ws + o); o += 786432;
    __bf16* decWe= (__bf16*)(ws + o); o += 262144;    // 2048*256 bf16
    __bf16* WdC  = (__bf16*)(ws + o); o += 1572864;   // 2048*1536 bf16
    __bf16* fcWh = (__bf16*)(ws + o); o += 262144;    // 512*1024 bf16
    __bf16* fcWc = (__bf16*)(ws + o); o += 262144;
    __bf16* foWb = (__bf16*)(ws + o); o += 32768;     // 128*512 bf16
    __bf16* hfb  = (__bf16*)(ws + o); o += 262144;
    __bf16* cfb  = (__bf16*)(ws + o); o += 262144;
    __bf16* ctxh = (__bf16*)(ws + o); o += 393216;    // 512*1536 bf16
    float* hid_h = ws + o;            o += 262144;
    float* hid_c = ws + o;            o += 262144;
    float* ehv   = ws + o;            o += 512;
    float* energy= ws + o;            o += 32768;
    float* attn  = ws + o;            o += 32768;
    float* ctx   = ws + o;            o += 524288;
    float* D0    = ws + o;            o += 1048576;   // 512*2048 f32
    float* D0s   = ws + o;            o += 1048576;   // swizzled [b][j][4g]
    float* bias_f= ws + o;            o += 2048;
    float* bias_b= ws + o;            o += 2048;
    float* bias_d= ws + o;            o += 2048;
    __bf16* h_new= (__bf16*)(ws + o); o += 6160384;   // 24064*512 bf16
    unsigned int* cnt = (unsigned int*)(ws + o); o += 1024;   // 64 steps x 16 groups

    // ---- prep ----
    embed_bf16<<<4096, 256, 0, stream>>>(src, enc_emb, embE, SRCL * BATCH);
    embed_bf16<<<3008, 256, 0, stream>>>(trg, dec_emb, embD, (TRGL - 1) * BATCH);
    zero_kernel<<<4096, 256, 0, stream>>>(zbase, 1048576);     // h0,h1,cbuf
    zero_kernel<<<4, 256, 0, stream>>>((float*)cnt, 1024);     // barrier counters
    bias_prep<<<8, 256, 0, stream>>>(bih_f, bhh_f, bih_b, bhh_b, dec_bih, dec_bhh,
                                     bias_f, bias_b, bias_d);
    wcat_bf16<<<768, 256, 0, stream>>>(Wih_f, Whh_f, WcF);
    wcat_bf16<<<768, 256, 0, stream>>>(Wih_b, Whh_b, WcB);
    decw_bf16<<<256, 256, 0, stream>>>(dec_Wih, decWe);
    wdcat_bf16<<<1536, 256, 0, stream>>>(dec_Wih, dec_Whh, WdC);
    conv_f2b<<<256, 256, 0, stream>>>(fc_h_W, fcWh, 65536);
    conv_f2b<<<256, 256, 0, stream>>>(fc_c_W, fcWc, 65536);
    fo_pad<<<32, 256, 0, stream>>>(fc_out_W, foWb);

    // ---- encoder: ONE persistent dispatch, 64 steps with in-kernel group barriers ----
    enc_scan<<<256, 256, 0, stream>>>(embE, h0, h1, cbuf, es, WcF, WcB,
                                      bias_f, bias_b, cnt);

    // ---- hidden projections (bf16 MFMA) ----
    cat_hfb<<<256, 256, 0, stream>>>(es, hfb);
    cat_cfb<<<256, 256, 0, stream>>>(cbuf, cfb);
    gmm_bf16<<<dim3(8, 8), 256, 0, stream>>>(hfb, fcWh, 1024, fc_h_b, hid_h, HSZ, HSZ);
    gmm_bf16<<<dim3(8, 8), 256, 0, stream>>>(cfb, fcWc, 1024, fc_c_b, hid_c, HSZ, HSZ);

    // ---- attention ----
    eh_kernel<<<128, 256, 0, stream>>>(hid_h, energy_W, energy_b, ehv);
    energy_kernel<<<8192, 256, 0, stream>>>(es, energy_W + HSZ, ehv, energy);
    softmax_kernel<<<128, 256, 0, stream>>>(energy, attn);
    context_kernel<<<512, 256, 0, stream>>>(attn, es, ctx);

    // ---- decoder batch-invariant: D0 = [ctx|hid_h] @ [Wih(:,:1024)|Whh]^T + bias ----
    cat_ctxh<<<384, 256, 0, stream>>>(ctx, hid_h, ctxh);
    gmm_bf16<<<dim3(32, 8), 256, 0, stream>>>(ctxh, WdC, 1536, bias_d, D0, G4, G4);
    d0_swz<<<4096, 256, 0, stream>>>(D0, D0s);

    // ---- decoder fused gates + pointwise -> h_new (bf16) ----
    dec_v4<<<dim3(16, 188), 256, 0, stream>>>(embD, decWe, D0s, hid_c, h_new);

    // ---- outputs ----
    zero_kernel<<<134, 256, 0, stream>>>(out, BATCH * ODIM);
    gmm_bf16<<<dim3(2, 376), 256, 0, stream>>>(h_new, foWb, HSZ, fc_out_b,
                                               out + (size_t)BATCH * ODIM, ODIM, ODIM);
}

// Round 5
// 1104.777 us; speedup vs baseline: 4.7226x; 4.7226x over previous
//
#include <hip/hip_runtime.h>
#include <cstddef>

#define BATCH 512
#define ESZ   256
#define HSZ   512
#define G4    2048      // 4*HS
#define SRCL  64
#define TRGL  48
#define ODIM  67

typedef __bf16  bf8v    __attribute__((ext_vector_type(8)));
typedef float   floatx4 __attribute__((ext_vector_type(4)));

__device__ __forceinline__ floatx4 MF(bf8v a, bf8v b, floatx4 c) {
    return __builtin_amdgcn_mfma_f32_16x16x32_bf16(a, b, c, 0, 0, 0);
}

// fast transcendentals: v_exp_f32 + v_rcp_f32
__device__ __forceinline__ float frcp(float x) { return __builtin_amdgcn_rcpf(x); }
__device__ __forceinline__ float fsig(float x) { return frcp(1.0f + __expf(-x)); }
__device__ __forceinline__ float ftanh(float x) { return 1.0f - 2.0f * frcp(1.0f + __expf(2.0f * x)); }

__device__ __forceinline__ bf8v cvt8(const float* __restrict__ s) {
    float4 a = *(const float4*)s;
    float4 b = *(const float4*)(s + 4);
    bf8v v;
    v[0] = (__bf16)a.x; v[1] = (__bf16)a.y; v[2] = (__bf16)a.z; v[3] = (__bf16)a.w;
    v[4] = (__bf16)b.x; v[5] = (__bf16)b.y; v[6] = (__bf16)b.z; v[7] = (__bf16)b.w;
    return v;
}

// ---------------- prep kernels ----------------
// decoder embedding, row-major bf16
__global__ void embed_bf16(const int* __restrict__ tok, const float* __restrict__ table,
                           __bf16* __restrict__ out, int n_rows) {
    int i = blockIdx.x * 256 + threadIdx.x;
    int row = i >> 5;
    if (row >= n_rows) return;
    int e = (i & 31) << 3;
    *(bf8v*)(out + (size_t)row * ESZ + e) = cvt8(table + (size_t)tok[row] * ESZ + e);
}

// encoder embedding straight into A-fragment order: Az[t][mt32][kt8][lane64][8]
__global__ void embed_swz(const int* __restrict__ tok, const float* __restrict__ table,
                          __bf16* __restrict__ Az) {
    int i = blockIdx.x * 256 + threadIdx.x;   // 1,048,576 chunks
    int lane = i & 63;
    int kt = (i >> 6) & 7;
    int mt = (i >> 9) & 31;
    int t  = i >> 14;
    int b = mt * 16 + (lane & 15);
    int k = kt * 32 + (lane >> 4) * 8;
    int tk = tok[t * BATCH + b];
    *(bf8v*)(Az + (size_t)i * 8) = cvt8(table + (size_t)tk * ESZ + k);
}

__global__ void zero_kernel(float* __restrict__ p, int n) {
    int i = blockIdx.x * 256 + threadIdx.x;
    if (i < n) p[i] = 0.f;
}

__global__ void bias_prep(const float* __restrict__ af, const float* __restrict__ bf,
                          const float* __restrict__ ab, const float* __restrict__ bb,
                          const float* __restrict__ ad, const float* __restrict__ bd,
                          float* __restrict__ of, float* __restrict__ ob, float* __restrict__ od) {
    int i = blockIdx.x * 256 + threadIdx.x;
    if (i < G4) { of[i] = af[i] + bf[i]; ob[i] = ab[i] + bb[i]; od[i] = ad[i] + bd[i]; }
}

// encoder weights into B-fragment order: Wz[jt32][g4][kt24][lane64][8]
// element: row = g*512 + jt*16 + (lane&15), k = kt*32 + (lane>>4)*8 (+e); k<256 -> Wih, else Whh
__global__ void wswz_bf16(const float* __restrict__ Wih, const float* __restrict__ Whh,
                          __bf16* __restrict__ Wz) {
    int i = blockIdx.x * 256 + threadIdx.x;   // 196,608 chunks
    int lane = i & 63;
    int rest = i >> 6;
    int kt = rest % 24;
    int gj = rest / 24;                        // jt*4+g
    int g = gj & 3, jt = gj >> 2;
    int row = g * 512 + jt * 16 + (lane & 15);
    int k = kt * 32 + (lane >> 4) * 8;
    const float* src = (k < ESZ) ? (Wih + (size_t)row * ESZ + k)
                                 : (Whh + (size_t)row * HSZ + (k - ESZ));
    *(bf8v*)(Wz + (size_t)i * 8) = cvt8(src);
}

// decWe[n][k] = dec_Wih[n][1024+k]  (2048 x 256 bf16)
__global__ void decw_bf16(const float* __restrict__ dec_Wih, __bf16* __restrict__ We) {
    int i = blockIdx.x * 256 + threadIdx.x;
    int n = i >> 5;
    int e = (i & 31) << 3;
    *(bf8v*)(We + (size_t)n * ESZ + e) =
        cvt8(dec_Wih + (size_t)n * (2 * HSZ + ESZ) + 2 * HSZ + e);
}

// WdC[n][0:1024]=dec_Wih[n][0:1024], [1024:1536]=dec_Whh[n]  (2048 x 1536 bf16)
__global__ void wdcat_bf16(const float* __restrict__ dec_Wih, const float* __restrict__ dec_Whh,
                           __bf16* __restrict__ Wd) {
    int i = blockIdx.x * 256 + threadIdx.x;
    int n = i / 192;
    int e = (i - n * 192) << 3;
    const float* src = (e < 1024) ? (dec_Wih + (size_t)n * 1280 + e)
                                  : (dec_Whh + (size_t)n * HSZ + (e - 1024));
    *(bf8v*)(Wd + (size_t)n * 1536 + e) = cvt8(src);
}

__global__ void conv_f2b(const float* __restrict__ src, __bf16* __restrict__ dst, int n8) {
    int i = blockIdx.x * 256 + threadIdx.x;
    if (i < n8) *(bf8v*)(dst + (size_t)i * 8) = cvt8(src + (size_t)i * 8);
}

// fc_out_W padded to 128 rows x 512 bf16
__global__ void fo_pad(const float* __restrict__ W, __bf16* __restrict__ dst) {
    int i = blockIdx.x * 256 + threadIdx.x;
    int r = i >> 6, e = (i & 63) << 3;
    bf8v v;
    if (r < ODIM) v = cvt8(W + (size_t)r * HSZ + e);
    else { for (int k = 0; k < 8; ++k) v[k] = (__bf16)0.f; }
    *(bf8v*)(dst + (size_t)r * HSZ + e) = v;
}

// hfb[r] = [es[63][r][0:512] | es[0][r][512:1024]]
__global__ void cat_hfb(const __bf16* __restrict__ es, __bf16* __restrict__ dst) {
    int i = blockIdx.x * 256 + threadIdx.x;
    int r = i >> 7, e = (i & 127) << 3;
    const __bf16* s = (e < HSZ) ? (es + ((size_t)(63 * BATCH + r)) * 1024 + e)
                                : (es + (size_t)r * 1024 + e);
    *(bf8v*)(dst + (size_t)r * 1024 + e) = *(const bf8v*)s;
}

// cfb[r] = bf16([cf[r] | cb[r]]) from cbuf fp32 [2][512][512]
__global__ void cat_cfb(const float* __restrict__ cbuf, __bf16* __restrict__ dst) {
    int i = blockIdx.x * 256 + threadIdx.x;
    int r = i >> 7, e = (i & 127) << 3;
    const float* s = (e < HSZ) ? (cbuf + (size_t)r * HSZ + e)
                               : (cbuf + (size_t)BATCH * HSZ + (size_t)r * HSZ + (e - HSZ));
    *(bf8v*)(dst + (size_t)r * 1024 + e) = cvt8(s);
}

// ctxh[r] = bf16([ctx[r] (1024) | hid_h[r] (512)])
__global__ void cat_ctxh(const float* __restrict__ ctx, const float* __restrict__ hid_h,
                         __bf16* __restrict__ dst) {
    int i = blockIdx.x * 256 + threadIdx.x;
    int r = i / 192;
    int e = (i - r * 192) << 3;
    const float* s = (e < 1024) ? (ctx + (size_t)r * 1024 + e)
                                : (hid_h + (size_t)r * HSZ + (e - 1024));
    *(bf8v*)(dst + (size_t)r * 1536 + e) = cvt8(s);
}

// D0s[(b*512+j)*4 + g] = D0[b*2048 + g*512 + j]
__global__ void d0_swz(const float* __restrict__ D0, float* __restrict__ D0s) {
    int i = blockIdx.x * 256 + threadIdx.x;   // 1048576
    int b = i >> 11, rest = i & 2047, g = rest >> 9, j = rest & 511;
    D0s[(((size_t)b * 512 + j) << 2) + g] = D0[i];
}

// ---------------- encoder step v5: all-coalesced fragment loads, no K-loop LDS ----------------
// gates = [x_t | h] @ Wcat^T + bias, fused LSTM. grid (16 j-tiles, 16 m-tiles, 2 dir), 128 thr.
// Block: 32m x 32j x 4 gates. Wave: 32m x 16j x 4g (acc[2][4]).
// Az: x in A-frag order; hPrev/hNext in A-frag order [dir][mt][kt][lane][8]; Wz in B-frag order.
__global__ __launch_bounds__(128) void enc_step5(
    const __bf16* __restrict__ Az, const __bf16* __restrict__ hPrev,
    __bf16* __restrict__ hNext, float* __restrict__ cbuf, __bf16* __restrict__ es,
    const __bf16* __restrict__ WzF, const __bf16* __restrict__ WzB,
    const float* __restrict__ biasF, const float* __restrict__ biasB, int t)
{
    __shared__ float cT[32 * 33];
    __shared__ float hT[32 * 33];

    const int dir = blockIdx.z;
    const int tt  = dir ? (SRCL - 1 - t) : t;
    const __bf16* Wz  = dir ? WzB : WzF;
    const float* bias = dir ? biasB : biasF;
    const int j0 = blockIdx.x * 32;
    const int m0 = blockIdx.y * 32;

    const int tid = threadIdx.x;
    const int w = tid >> 6, lane = tid & 63;
    const int quad = lane >> 4, l15 = lane & 15;
    const int jtw = blockIdx.x * 2 + w;       // j-tile-of-16 index (0..31)

    // stage c tile (32x32 f32) into LDS, coalesced
    {
        int r = tid >> 2, ch = tid & 3;
        const float* cp = cbuf + (size_t)dir * BATCH * HSZ + (size_t)(m0 + r) * HSZ + j0 + ch * 8;
        *(float4*)(&cT[r * 33 + ch * 8])     = *(const float4*)cp;
        *(float4*)(&cT[r * 33 + ch * 8 + 4]) = *(const float4*)(cp + 4);
    }

    floatx4 acc[2][4] = {};
    const int mt0 = m0 >> 4;
    const __bf16* ax0 = Az + ((((size_t)tt * 32 + mt0) * 8) << 9) + lane * 8;
    const __bf16* ax1 = ax0 + (8 << 9);
    const __bf16* ah0 = hPrev + ((((size_t)dir * 32 + mt0) * 16) << 9) + lane * 8;
    const __bf16* ah1 = ah0 + (16 << 9);
    const __bf16* bw  = Wz + (((size_t)jtw * 4 * 24) << 9) + lane * 8;

#pragma unroll 2
    for (int kt = 0; kt < 8; ++kt) {          // x part
        bf8v a0 = *(const bf8v*)(ax0 + ((size_t)kt << 9));
        bf8v a1 = *(const bf8v*)(ax1 + ((size_t)kt << 9));
#pragma unroll
        for (int g = 0; g < 4; ++g) {
            bf8v b = *(const bf8v*)(bw + (((size_t)(g * 24 + kt)) << 9));
            acc[0][g] = MF(a0, b, acc[0][g]);
            acc[1][g] = MF(a1, b, acc[1][g]);
        }
    }
#pragma unroll 2
    for (int kt = 0; kt < 16; ++kt) {         // h part
        bf8v a0 = *(const bf8v*)(ah0 + ((size_t)kt << 9));
        bf8v a1 = *(const bf8v*)(ah1 + ((size_t)kt << 9));
#pragma unroll
        for (int g = 0; g < 4; ++g) {
            bf8v b = *(const bf8v*)(bw + (((size_t)(g * 24 + 8 + kt)) << 9));
            acc[0][g] = MF(a0, b, acc[0][g]);
            acc[1][g] = MF(a1, b, acc[1][g]);
        }
    }

    __syncthreads();   // c tile staged

    // fused LSTM pointwise, all 4 gates in-register; results into LDS tiles
    const int jl = w * 16 + l15;
    const int j = j0 + jl;
    const float b0 = bias[j], b1 = bias[HSZ + j], b2 = bias[2 * HSZ + j], b3 = bias[3 * HSZ + j];
#pragma unroll
    for (int ms = 0; ms < 2; ++ms) {
#pragma unroll
        for (int r = 0; r < 4; ++r) {
            int ml = ms * 16 + quad * 4 + r;
            float gi = acc[ms][0][r] + b0;
            float gf = acc[ms][1][r] + b1;
            float gg = acc[ms][2][r] + b2;
            float go = acc[ms][3][r] + b3;
            float cn = fsig(gf) * cT[ml * 33 + jl] + fsig(gi) * ftanh(gg);
            cT[ml * 33 + jl] = cn;
            hT[ml * 33 + jl] = fsig(go) * ftanh(cn);
        }
    }
    __syncthreads();

    // coalesced stores: c (row-major), h (A-frag order), es (row-major)
    const size_t cb = (size_t)dir * BATCH * HSZ;
#pragma unroll
    for (int s = 0; s < 2; ++s) {
        int task = tid + s * 128;
        int r = task >> 3, ch = task & 7;
        *(float4*)(cbuf + cb + (size_t)(m0 + r) * HSZ + j0 + ch * 4) =
            *(const float4*)(&cT[r * 33 + ch * 4]);
    }
    {
        int mtl = tid >> 6;                   // 0..1
        int ln = tid & 63;
        int q2 = ln >> 4, l2 = ln & 15;
        const float* hp = &hT[(mtl * 16 + l2) * 33 + q2 * 8];
        bf8v v;
#pragma unroll
        for (int e = 0; e < 8; ++e) v[e] = (__bf16)hp[e];
        size_t chunk = ((((size_t)dir * 32 + mt0 + mtl) * 16) + (j0 >> 5)) * 64 + ln;
        *(bf8v*)(hNext + chunk * 8) = v;
    }
    {
        int r = tid >> 2, ch = tid & 3;
        const float* hp = &hT[r * 33 + ch * 8];
        bf8v v;
#pragma unroll
        for (int e = 0; e < 8; ++e) v[e] = (__bf16)hp[e];
        *(bf8v*)(es + ((size_t)tt * BATCH + m0 + r) * 1024 + dir * HSZ + j0 + ch * 8) = v;
    }
}

// ---------------- decoder: LDS-staged K=256 GEMM + fused LSTM (round-4, verified) ----------------
#define DA_STR 264   // 256 + 8 bf16 pad
__global__ __launch_bounds__(256) void dec_v4(
    const __bf16* __restrict__ embD, const __bf16* __restrict__ We,
    const float* __restrict__ D0s, const float* __restrict__ hidc,
    __bf16* __restrict__ h_new)
{
    __shared__ __bf16 As[128 * DA_STR];
    __shared__ __bf16 Bs2[128 * DA_STR];

    const int m0 = blockIdx.y * 128;
    const int j0 = blockIdx.x * 32;
    const int tid = threadIdx.x;
    const int w = tid >> 6, lane = tid & 63;
    const int quad = lane >> 4, l15 = lane & 15;
    const int mh = (w & 1) * 64;
    const int ghi = w >> 1;
    const int jl = l15 + ghi * 16;

#pragma unroll 4
    for (int i = 0; i < 16; ++i) {
        int idx = tid + i * 256;
        int r = idx >> 5, ch = idx & 31;
        *(bf8v*)(&As[r * DA_STR + ch * 8]) =
            *(const bf8v*)(embD + (size_t)(m0 + r) * ESZ + ch * 8);
        int gate = (r >> 4) & 3;
        int jr = (r & 15) + ((r >> 6) << 4);
        *(bf8v*)(&Bs2[r * DA_STR + ch * 8]) =
            *(const bf8v*)(We + (size_t)(gate * HSZ + j0 + jr) * ESZ + ch * 8);
    }
    __syncthreads();

    floatx4 acc[4][4] = {};
    const __bf16* BhB = &Bs2[(ghi * 64 + l15) * DA_STR + quad * 8];
#pragma unroll 4
    for (int kt = 0; kt < 8; ++kt) {
        bf8v a[4];
#pragma unroll
        for (int ms = 0; ms < 4; ++ms)
            a[ms] = *(const bf8v*)(&As[(mh + ms * 16 + l15) * DA_STR + quad * 8 + kt * 32]);
#pragma unroll
        for (int g = 0; g < 4; ++g) {
            bf8v b = *(const bf8v*)(BhB + g * 16 * DA_STR + kt * 32);
#pragma unroll
            for (int ms = 0; ms < 4; ++ms)
                acc[ms][g] = MF(a[ms], b, acc[ms][g]);
        }
    }

    const int j = j0 + jl;
#pragma unroll
    for (int ms = 0; ms < 4; ++ms) {
        int mr = m0 + mh + ms * 16 + quad * 4;
#pragma unroll
        for (int r = 0; r < 4; ++r) {
            int m = mr + r;
            int b = m & (BATCH - 1);
            floatx4 d0 = *(const floatx4*)(D0s + (((size_t)b * 512 + j) << 2));
            float gi = acc[ms][0][r] + d0[0];
            float gf = acc[ms][1][r] + d0[1];
            float gg = acc[ms][2][r] + d0[2];
            float go = acc[ms][3][r] + d0[3];
            float cn = fsig(gf) * hidc[(size_t)b * HSZ + j] + fsig(gi) * ftanh(gg);
            h_new[(size_t)m * HSZ + j] = (__bf16)(fsig(go) * ftanh(cn));
        }
    }
}

// ---------------- generic bf16 MFMA GEMM: C = A @ B^T + bias (fp32 out) ----------------
__global__ __launch_bounds__(256) void gmm_bf16(
    const __bf16* __restrict__ A, const __bf16* __restrict__ B, int K,
    const float* __restrict__ bias, float* __restrict__ C, int ldc, int N)
{
    const int tid = threadIdx.x;
    const int w = tid >> 6, lane = tid & 63;
    const int quad = lane >> 4, l15 = lane & 15;
    const int n0 = blockIdx.x * 64;
    const int mA = blockIdx.y * 64 + w * 16 + l15;

    const __bf16* Ar = A + (size_t)mA * K + quad * 8;
    const __bf16* Br[4];
#pragma unroll
    for (int ns = 0; ns < 4; ++ns)
        Br[ns] = B + (size_t)(n0 + ns * 16 + l15) * K + quad * 8;

    floatx4 acc[4] = {};
    const int KT = K >> 5;
#pragma unroll 4
    for (int kt = 0; kt < KT; ++kt) {
        bf8v a = *(const bf8v*)(Ar + kt * 32);
#pragma unroll
        for (int ns = 0; ns < 4; ++ns) {
            bf8v b = *(const bf8v*)(Br[ns] + kt * 32);
            acc[ns] = MF(a, b, acc[ns]);
        }
    }
    const int mb = blockIdx.y * 64 + w * 16 + quad * 4;
#pragma unroll
    for (int ns = 0; ns < 4; ++ns) {
        int n = n0 + ns * 16 + l15;
        if (n < N) {
#pragma unroll
            for (int r = 0; r < 4; ++r)
                C[(size_t)(mb + r) * ldc + n] = acc[ns][r] + bias[n];
        }
    }
}

// ---------------- attention ----------------
__global__ void eh_kernel(const float* __restrict__ hid_h, const float* __restrict__ eW,
                          const float* __restrict__ eb, float* __restrict__ eh) {
    int w = blockIdx.x * 4 + (threadIdx.x >> 6);
    int lane = threadIdx.x & 63;
    if (w >= BATCH) return;
    float s = 0.f;
    for (int k = lane; k < HSZ; k += 64) s += hid_h[(size_t)w * HSZ + k] * eW[k];
    for (int off = 32; off; off >>= 1) s += __shfl_down(s, off);
    if (lane == 0) eh[w] = s + eb[0];
}

__global__ void energy_kernel(const __bf16* __restrict__ es, const float* __restrict__ eW2,
                              const float* __restrict__ eh, float* __restrict__ energy) {
    int w = blockIdx.x * 4 + (threadIdx.x >> 6);
    int lane = threadIdx.x & 63;
    int s = w >> 9, b = w & 511;
    const __bf16* row = es + ((size_t)s * BATCH + b) * (2 * HSZ);
    float v = 0.f;
    for (int k = lane; k < 2 * HSZ; k += 64) v += (float)row[k] * eW2[k];
    for (int off = 32; off; off >>= 1) v += __shfl_down(v, off);
    if (lane == 0) energy[(size_t)s * BATCH + b] = fmaxf(v + eh[b], 0.f);
}

__global__ void softmax_kernel(const float* __restrict__ energy, float* __restrict__ attn) {
    int b = blockIdx.x * 4 + (threadIdx.x >> 6);
    int lane = threadIdx.x & 63;
    if (b >= BATCH) return;
    float v = energy[(size_t)lane * BATCH + b];
    float m = v;
    for (int off = 32; off; off >>= 1) m = fmaxf(m, __shfl_xor(m, off));
    float e = __expf(v - m);
    float sum = e;
    for (int off = 32; off; off >>= 1) sum += __shfl_xor(sum, off);
    attn[(size_t)lane * BATCH + b] = e / sum;
}

__global__ void context_kernel(const float* __restrict__ attn, const __bf16* __restrict__ es,
                               float* __restrict__ ctx) {
    int b = blockIdx.x;
    int j = threadIdx.x * 4;
    float a0 = 0.f, a1 = 0.f, a2 = 0.f, a3 = 0.f;
    for (int s = 0; s < SRCL; ++s) {
        float a = attn[(size_t)s * BATCH + b];
        const __bf16* r = es + ((size_t)s * BATCH + b) * (2 * HSZ) + j;
        a0 += a * (float)r[0]; a1 += a * (float)r[1];
        a2 += a * (float)r[2]; a3 += a * (float)r[3];
    }
    float4 o = make_float4(a0, a1, a2, a3);
    *(float4*)(ctx + (size_t)b * (2 * HSZ) + j) = o;
}

// ---------------- launch ----------------
extern "C" void kernel_launch(void* const* d_in, const int* in_sizes, int n_in,
                              void* d_out, int out_size, void* d_ws, size_t ws_size,
                              hipStream_t stream) {
    const int*   src      = (const int*)d_in[0];
    const int*   trg      = (const int*)d_in[1];
    const float* enc_emb  = (const float*)d_in[2];
    const float* Wih_f    = (const float*)d_in[3];
    const float* Whh_f    = (const float*)d_in[4];
    const float* bih_f    = (const float*)d_in[5];
    const float* bhh_f    = (const float*)d_in[6];
    const float* Wih_b    = (const float*)d_in[7];
    const float* Whh_b    = (const float*)d_in[8];
    const float* bih_b    = (const float*)d_in[9];
    const float* bhh_b    = (const float*)d_in[10];
    const float* fc_h_W   = (const float*)d_in[11];
    const float* fc_h_b   = (const float*)d_in[12];
    const float* fc_c_W   = (const float*)d_in[13];
    const float* fc_c_b   = (const float*)d_in[14];
    const float* dec_emb  = (const float*)d_in[15];
    const float* dec_Wih  = (const float*)d_in[16];
    const float* dec_Whh  = (const float*)d_in[17];
    const float* dec_bih  = (const float*)d_in[18];
    const float* dec_bhh  = (const float*)d_in[19];
    const float* energy_W = (const float*)d_in[20];
    const float* energy_b = (const float*)d_in[21];
    const float* fc_out_W = (const float*)d_in[22];
    const float* fc_out_b = (const float*)d_in[23];
    float* out = (float*)d_out;

    // workspace layout (float units, all 16B aligned)
    float* ws = (float*)d_ws;
    size_t o = 0;
    __bf16* Az   = (__bf16*)(ws + o); o += 4194304;   // 64*32*8*64*8 bf16 (x A-frags)
    __bf16* embD = (__bf16*)(ws + o); o += 3080192;   // 47*512*256 bf16
    __bf16* es   = (__bf16*)(ws + o); o += 16777216;  // 64*512*1024 bf16
    float* zbase = ws + o;                            // h0,h1,cbuf contiguous
    __bf16* h0   = (__bf16*)(ws + o); o += 262144;    // swizzled h: 2*32*16*64*8 bf16
    __bf16* h1   = (__bf16*)(ws + o); o += 262144;
    float*  cbuf = ws + o;            o += 524288;    // 2*512*512 f32
    __bf16* WzF  = (__bf16*)(ws + o); o += 786432;    // 32*4*24*64*8 bf16 (B-frags)
    __bf16* WzB  = (__bf16*)(ws + o); o += 786432;
    __bf16* decWe= (__bf16*)(ws + o); o += 262144;    // 2048*256 bf16
    __bf16* WdC  = (__bf16*)(ws + o); o += 1572864;   // 2048*1536 bf16
    __bf16* fcWh = (__bf16*)(ws + o); o += 262144;    // 512*1024 bf16
    __bf16* fcWc = (__bf16*)(ws + o); o += 262144;
    __bf16* foWb = (__bf16*)(ws + o); o += 32768;     // 128*512 bf16
    __bf16* hfb  = (__bf16*)(ws + o); o += 262144;
    __bf16* cfb  = (__bf16*)(ws + o); o += 262144;
    __bf16* ctxh = (__bf16*)(ws + o); o += 393216;    // 512*1536 bf16
    float* hid_h = ws + o;            o += 262144;
    float* hid_c = ws + o;            o += 262144;
    float* ehv   = ws + o;            o += 512;
    float* energy= ws + o;            o += 32768;
    float* attn  = ws + o;            o += 32768;
    float* ctx   = ws + o;            o += 524288;
    float* D0    = ws + o;            o += 1048576;   // 512*2048 f32
    float* D0s   = ws + o;            o += 1048576;   // swizzled [b][j][4g]
    float* bias_f= ws + o;            o += 2048;
    float* bias_b= ws + o;            o += 2048;
    float* bias_d= ws + o;            o += 2048;
    __bf16* h_new= (__bf16*)(ws + o); o += 6160384;   // 24064*512 bf16

    // ---- prep ----
    embed_swz<<<4096, 256, 0, stream>>>(src, enc_emb, Az);
    embed_bf16<<<3008, 256, 0, stream>>>(trg, dec_emb, embD, (TRGL - 1) * BATCH);
    zero_kernel<<<4096, 256, 0, stream>>>(zbase, 1048576);     // h0,h1,cbuf
    bias_prep<<<8, 256, 0, stream>>>(bih_f, bhh_f, bih_b, bhh_b, dec_bih, dec_bhh,
                                     bias_f, bias_b, bias_d);
    wswz_bf16<<<768, 256, 0, stream>>>(Wih_f, Whh_f, WzF);
    wswz_bf16<<<768, 256, 0, stream>>>(Wih_b, Whh_b, WzB);
    decw_bf16<<<256, 256, 0, stream>>>(dec_Wih, decWe);
    wdcat_bf16<<<1536, 256, 0, stream>>>(dec_Wih, dec_Whh, WdC);
    conv_f2b<<<256, 256, 0, stream>>>(fc_h_W, fcWh, 65536);
    conv_f2b<<<256, 256, 0, stream>>>(fc_c_W, fcWc, 65536);
    fo_pad<<<32, 256, 0, stream>>>(fc_out_W, foWb);

    // ---- encoder scan: 64 per-step launches, all operand loads coalesced frag-order ----
    for (int t = 0; t < SRCL; ++t) {
        const __bf16* hp = (t & 1) ? h1 : h0;
        __bf16*       hn = (t & 1) ? h0 : h1;
        enc_step5<<<dim3(16, 16, 2), 128, 0, stream>>>(
            Az, hp, hn, cbuf, es, WzF, WzB, bias_f, bias_b, t);
    }

    // ---- hidden projections (bf16 MFMA) ----
    cat_hfb<<<256, 256, 0, stream>>>(es, hfb);
    cat_cfb<<<256, 256, 0, stream>>>(cbuf, cfb);
    gmm_bf16<<<dim3(8, 8), 256, 0, stream>>>(hfb, fcWh, 1024, fc_h_b, hid_h, HSZ, HSZ);
    gmm_bf16<<<dim3(8, 8), 256, 0, stream>>>(cfb, fcWc, 1024, fc_c_b, hid_c, HSZ, HSZ);

    // ---- attention ----
    eh_kernel<<<128, 256, 0, stream>>>(hid_h, energy_W, energy_b, ehv);
    energy_kernel<<<8192, 256, 0, stream>>>(es, energy_W + HSZ, ehv, energy);
    softmax_kernel<<<128, 256, 0, stream>>>(energy, attn);
    context_kernel<<<512, 256, 0, stream>>>(attn, es, ctx);

    // ---- decoder batch-invariant: D0 = [ctx|hid_h] @ [Wih(:,:1024)|Whh]^T + bias ----
    cat_ctxh<<<384, 256, 0, stream>>>(ctx, hid_h, ctxh);
    gmm_bf16<<<dim3(32, 8), 256, 0, stream>>>(ctxh, WdC, 1536, bias_d, D0, G4, G4);
    d0_swz<<<4096, 256, 0, stream>>>(D0, D0s);

    // ---- decoder fused gates + pointwise -> h_new (bf16) ----
    dec_v4<<<dim3(16, 188), 256, 0, stream>>>(embD, decWe, D0s, hid_c, h_new);

    // ---- outputs ----
    zero_kernel<<<134, 256, 0, stream>>>(out, BATCH * ODIM);
    gmm_bf16<<<dim3(2, 376), 256, 0, stream>>>(h_new, foWb, HSZ, fc_out_b,
                                               out + (size_t)BATCH * ODIM, ODIM, ODIM);
}